// Round 2
// baseline (930.423 us; speedup 1.0000x reference)
//
#include <hip/hip_runtime.h>
#include <stdint.h>

#define B_  4
#define S_  2048
#define DM_ 2048
#define NH_ 16
#define HD_ 128

typedef unsigned short u16;
typedef __attribute__((ext_vector_type(8))) short short8;
typedef __attribute__((ext_vector_type(8))) unsigned short u16x8;
typedef __attribute__((ext_vector_type(4))) float f32x4;

__device__ __forceinline__ u16 f2b(float f){
  union { float f; unsigned u; } v; v.f = f;
  return (u16)((v.u + 0x7fffu + ((v.u >> 16) & 1u)) >> 16);
}
__device__ __forceinline__ float b2f(u16 b){
  union { unsigned u; float f; } v; v.u = ((unsigned)b) << 16; return v.f;
}
__device__ __forceinline__ void gld_lds16(const void* g, void* l){
  __builtin_amdgcn_global_load_lds(
    (const __attribute__((address_space(1))) unsigned int*)(uintptr_t)g,
    (__attribute__((address_space(3))) unsigned int*)(uintptr_t)l, 16, 0, 0);
}

// ---------------- fp32 -> bf16 convert (vectorized) ----------------
__global__ void k_convert(const float* __restrict__ in, u16* __restrict__ out, int n){
  int i = (blockIdx.x * 256 + threadIdx.x) * 8;
  if (i >= n) return;
  float4 a = *(const float4*)(in + i);
  float4 b = *(const float4*)(in + i + 4);
  u16x8 o;
  o[0]=f2b(a.x); o[1]=f2b(a.y); o[2]=f2b(a.z); o[3]=f2b(a.w);
  o[4]=f2b(b.x); o[5]=f2b(b.y); o[6]=f2b(b.z); o[7]=f2b(b.w);
  *(u16x8*)(out + i) = o;
}

// ------------- transpose + convert: in[R][C] f32 -> out[C][R] bf16 -------------
__global__ void k_transpose_cvt(const float* __restrict__ in, u16* __restrict__ out,
                                int R, int C){
  __shared__ u16 tile[32][33];
  int tx = threadIdx.x, ty = threadIdx.y;
  int c0 = blockIdx.x * 32, r0 = blockIdx.y * 32;
  #pragma unroll
  for (int i = 0; i < 4; i++){
    int r = r0 + ty + i * 8;
    tile[ty + i*8][tx] = f2b(in[(size_t)r * C + c0 + tx]);
  }
  __syncthreads();
  #pragma unroll
  for (int i = 0; i < 4; i++){
    int c = c0 + ty + i * 8;
    out[(size_t)c * R + r0 + tx] = tile[tx][ty + i*8];
  }
}

// ---------------- GEMM (A[M][2048] x BT[N][2048]^T), m97 structure ----------------
// EPI==0: QKV epilogue (scatter to Q/K per-head layout, V transposed)
// EPI==1: fp32 out + bias
template<int EPI>
__global__ __launch_bounds__(256, 2) void k_gemm_bt(
    const u16* __restrict__ A, const u16* __restrict__ BT,
    const float* __restrict__ bias,
    u16* __restrict__ Qd, u16* __restrict__ Kd, u16* __restrict__ Vd,
    float* __restrict__ Cout)
{
  __shared__ u16 As[128 * 32];
  __shared__ u16 Bs[128 * 32];
  const int lane = threadIdx.x & 63;
  const int wid  = threadIdx.x >> 6;
  const int wr = wid >> 1, wc = wid & 1;
  const int m0 = blockIdx.x * 128;
  const int n0 = blockIdx.y * 128;
  f32x4 acc[4][4] = {};
  const int fr = lane & 15;
  const int ks = (lane >> 4) * 8;

  for (int k0 = 0; k0 < 2048; k0 += 32){
    __syncthreads();
    #pragma unroll
    for (int t = 0; t < 2; t++){
      const int ob  = wid * 2048 + t * 1024 + lane * 16;  // byte offset in 8KB tile
      const int row = ob >> 6, colb = ob & 63;
      gld_lds16(A  + (size_t)(m0 + row) * 2048 + k0 + (colb >> 1),
                (char*)As + wid * 2048 + t * 1024);
      gld_lds16(BT + (size_t)(n0 + row) * 2048 + k0 + (colb >> 1),
                (char*)Bs + wid * 2048 + t * 1024);
    }
    __syncthreads();
    short8 af[4], bf[4];
    #pragma unroll
    for (int i = 0; i < 4; i++) af[i] = *(const short8*)&As[(wr*64 + i*16 + fr)*32 + ks];
    #pragma unroll
    for (int i = 0; i < 4; i++) bf[i] = *(const short8*)&Bs[(wc*64 + i*16 + fr)*32 + ks];
    #pragma unroll
    for (int i = 0; i < 4; i++)
      #pragma unroll
      for (int j = 0; j < 4; j++)
        acc[i][j] = __builtin_amdgcn_mfma_f32_16x16x32_bf16(af[i], bf[j], acc[i][j], 0, 0, 0);
  }

  const int rowb = m0 + wr*64 + (lane >> 4) * 4;
  const int colb = n0 + wc*64 + (lane & 15);
  #pragma unroll
  for (int ni = 0; ni < 4; ni++){
    const int col = colb + ni * 16;
    const float bv = bias[col];
    if (EPI == 0){
      const int qkv = col >> 11, hd = col & 2047, h = hd >> 7, d = hd & 127;
      u16* dst = (qkv == 0) ? Qd : ((qkv == 1) ? Kd : Vd);
      #pragma unroll
      for (int mi = 0; mi < 4; mi++){
        f32x4 c = acc[mi][ni];
        #pragma unroll
        for (int j = 0; j < 4; j++){
          const int row = rowb + mi * 16 + j;
          const int b = row >> 11, s = row & 2047;
          size_t idx;
          if (qkv == 2) idx = ((size_t)((b * NH_ + h) * HD_ + d)) * S_ + s;  // V transposed
          else          idx = ((size_t)((b * NH_ + h) * S_  + s)) * HD_ + d;
          dst[idx] = f2b(c[j] + bv);
        }
      }
    } else {
      #pragma unroll
      for (int mi = 0; mi < 4; mi++){
        f32x4 c = acc[mi][ni];
        #pragma unroll
        for (int j = 0; j < 4; j++){
          const int row = rowb + mi * 16 + j;
          Cout[(size_t)row * 2048 + col] = c[j] + bv;
        }
      }
    }
  }
}

// ---------------- RoPE (interleaved pairs), in-place on Q and K ----------------
__global__ void k_rope(u16* __restrict__ Qb, u16* __restrict__ Kb,
                       const float* __restrict__ rc, const float* __restrict__ rs){
  const int gid = blockIdx.x * 256 + threadIdx.x;
  const int seg = gid & 3;
  const int row = gid >> 2;                 // 0 .. 2*B*NH*S
  const int NR  = B_ * NH_ * S_;
  u16* base = (row < NR) ? (Qb + (size_t)row * HD_) : (Kb + (size_t)(row - NR) * HD_);
  const int s  = row & (S_ - 1);
  const int d0 = seg * 32;                  // 16 pairs
  u16x8 v[4];
  #pragma unroll
  for (int t = 0; t < 4; t++) v[t] = *(u16x8*)(base + d0 + t * 8);
  float c[16], sn[16];
  const float4* cp = (const float4*)(rc + (size_t)s * 64 + seg * 16);
  const float4* sp = (const float4*)(rs + (size_t)s * 64 + seg * 16);
  #pragma unroll
  for (int t = 0; t < 4; t++){
    float4 cv = cp[t], sv = sp[t];
    c[t*4+0]=cv.x; c[t*4+1]=cv.y; c[t*4+2]=cv.z; c[t*4+3]=cv.w;
    sn[t*4+0]=sv.x; sn[t*4+1]=sv.y; sn[t*4+2]=sv.z; sn[t*4+3]=sv.w;
  }
  #pragma unroll
  for (int p = 0; p < 16; p++){
    int t = p >> 2, l = (2 * p) & 7;
    float e = b2f(v[t][l]), o = b2f(v[t][l + 1]);
    v[t][l]     = f2b(e * c[p] - o * sn[p]);
    v[t][l + 1] = f2b(e * sn[p] + o * c[p]);
  }
  #pragma unroll
  for (int t = 0; t < 4; t++) *(u16x8*)(base + d0 + t * 8) = v[t];
}

// ---------------- causal flash attention ----------------
// grid (S/64, B*NH), 256 thr. Q [bh][s][128], K [bh][s][128], Vt [bh][128][s].
#define QBLK 64
#define KVB  32
__global__ __launch_bounds__(256, 2) void k_attn(
    const u16* __restrict__ Qb, const u16* __restrict__ Kb,
    const u16* __restrict__ Vtb, u16* __restrict__ Ob)
{
  const int bh = blockIdx.y, qt = blockIdx.x;
  const int lane = threadIdx.x & 63, wid = threadIdx.x >> 6;
  const int b = bh >> 4, h = bh & 15;
  const u16* Qp = Qb  + (size_t)bh * S_ * HD_;
  const u16* Kp = Kb  + (size_t)bh * S_ * HD_;
  const u16* Vp = Vtb + (size_t)bh * HD_ * S_;
  __shared__ u16 Ks[KVB * HD_];     // [kv][d], XOR-swizzled
  __shared__ u16 Vs[HD_ * KVB];     // [d][kv], XOR-swizzled
  __shared__ u16 Ps[4][16 * KVB];   // per-wave P, XOR-swizzled

  const int q0 = qt * QBLK + wid * 16;
  short8 qf[4];
  {
    const u16* qrow = Qp + (size_t)(q0 + (lane & 15)) * HD_ + (lane >> 4) * 8;
    #pragma unroll
    for (int kk = 0; kk < 4; kk++) qf[kk] = *(const short8*)(qrow + kk * 32);
  }
  f32x4 oacc[8] = {};
  float mrun[4], lrun[4];
  #pragma unroll
  for (int j = 0; j < 4; j++){ mrun[j] = -__builtin_inff(); lrun[j] = 0.f; }
  const float scale = 0.08838834764831845f;  // 1/sqrt(128)
  const int kv_end = qt * QBLK + QBLK;

  for (int kv0 = 0; kv0 < kv_end; kv0 += KVB){
    __syncthreads();
    {
      const int e0 = threadIdx.x * 16;
      #pragma unroll
      for (int t = 0; t < 2; t++){
        const int e = e0 + t * 8;
        // K tile: [kv][128]
        int r = e >> 7, cc = e & 127;
        u16x8 kv8 = *(const u16x8*)(Kp + (size_t)(kv0 + r) * HD_ + cc);
        *(u16x8*)((char*)Ks + ((r * 256 + cc * 2) ^ ((r & 7) << 4))) = kv8;
        // V tile (already transposed in global): [d][32]
        int dd = e >> 5, ck = e & 31;
        u16x8 vv8 = *(const u16x8*)(Vp + (size_t)dd * S_ + kv0 + ck);
        *(u16x8*)((char*)Vs + ((dd * 64 + ck * 2) ^ ((dd & 7) << 4))) = vv8;
      }
    }
    __syncthreads();
    const bool active = (kv0 <= q0 + 15);
    if (active){
      f32x4 sacc[2] = {};
      #pragma unroll
      for (int nf = 0; nf < 2; nf++){
        const int krow = nf * 16 + (lane & 15);
        #pragma unroll
        for (int kk = 0; kk < 4; kk++){
          const int ba = (krow * 256 + (kk * 32 + (lane >> 4) * 8) * 2) ^ ((krow & 7) << 4);
          short8 kf = *(const short8*)((const char*)Ks + ba);
          sacc[nf] = __builtin_amdgcn_mfma_f32_16x16x32_bf16(qf[kk], kf, sacc[nf], 0, 0, 0);
        }
      }
      const int qrow_ = q0 + (lane >> 4) * 4;
      const int kcA = kv0 + (lane & 15), kcB = kcA + 16;
      float sA[4], sB[4];
      #pragma unroll
      for (int j = 0; j < 4; j++){
        sA[j] = (kcA <= qrow_ + j) ? sacc[0][j] * scale : -__builtin_inff();
        sB[j] = (kcB <= qrow_ + j) ? sacc[1][j] * scale : -__builtin_inff();
      }
      float rmax[4];
      #pragma unroll
      for (int j = 0; j < 4; j++) rmax[j] = fmaxf(sA[j], sB[j]);
      #pragma unroll
      for (int m = 1; m < 16; m <<= 1)
        #pragma unroll
        for (int j = 0; j < 4; j++) rmax[j] = fmaxf(rmax[j], __shfl_xor(rmax[j], m, 16));
      float pA[4], pB[4], rsum[4], sc_[4];
      #pragma unroll
      for (int j = 0; j < 4; j++){
        float mnew = fmaxf(mrun[j], rmax[j]);
        sc_[j] = __expf(mrun[j] - mnew);
        pA[j]  = __expf(sA[j] - mnew);
        pB[j]  = __expf(sB[j] - mnew);
        mrun[j] = mnew;
        rsum[j] = pA[j] + pB[j];
      }
      #pragma unroll
      for (int m = 1; m < 16; m <<= 1)
        #pragma unroll
        for (int j = 0; j < 4; j++) rsum[j] += __shfl_xor(rsum[j], m, 16);
      #pragma unroll
      for (int j = 0; j < 4; j++) lrun[j] = lrun[j] * sc_[j] + rsum[j];
      #pragma unroll
      for (int g = 0; g < 8; g++)
        #pragma unroll
        for (int j = 0; j < 4; j++) oacc[g][j] *= sc_[j];
      // write P (bf16) to per-wave LDS, swizzled
      {
        char* pp = (char*)Ps[wid];
        const int prow = (lane >> 4) * 4, pc = (lane & 15);
        #pragma unroll
        for (int j = 0; j < 4; j++){
          int r = prow + j;
          *(u16*)(pp + (((r * 64 + pc * 2)        ) ^ ((r & 7) << 4))) = f2b(pA[j]);
          *(u16*)(pp + (((r * 64 + (pc + 16) * 2) ) ^ ((r & 7) << 4))) = f2b(pB[j]);
        }
        const int r2 = (lane & 15);
        short8 pf = *(const short8*)(pp + ((r2 * 64 + ((lane >> 4) * 8) * 2) ^ ((r2 & 7) << 4)));
        #pragma unroll
        for (int g = 0; g < 8; g++){
          const int dd = g * 16 + (lane & 15);
          const int ba = (dd * 64 + ((lane >> 4) * 8) * 2) ^ ((dd & 7) << 4);
          short8 vf = *(const short8*)((const char*)Vs + ba);
          oacc[g] = __builtin_amdgcn_mfma_f32_16x16x32_bf16(pf, vf, oacc[g], 0, 0, 0);
        }
      }
    }
  }
  // epilogue: normalize + store
  const int srow = q0 + (lane >> 4) * 4;
  #pragma unroll
  for (int j = 0; j < 4; j++){
    const float inv = 1.0f / lrun[j];
    u16* orow = Ob + ((size_t)(b * S_ + srow + j) * DM_) + h * HD_;
    #pragma unroll
    for (int g = 0; g < 8; g++)
      orow[g * 16 + (lane & 15)] = f2b(oacc[g][j] * inv);
  }
}

extern "C" void kernel_launch(void* const* d_in, const int* in_sizes, int n_in,
                              void* d_out, int out_size, void* d_ws, size_t ws_size,
                              hipStream_t stream) {
  const float* x     = (const float*)d_in[0];
  const float* w_qkv = (const float*)d_in[1];
  const float* b_qkv = (const float*)d_in[2];
  const float* w_out = (const float*)d_in[3];
  const float* b_out = (const float*)d_in[4];
  const float* rc    = (const float*)d_in[5];
  const float* rs    = (const float*)d_in[6];
  char* ws = (char*)d_ws;
  u16* xb    = (u16*)(ws);                  //  32 MB  x bf16 [8192][2048]  (reused as AO after GEMM1)
  u16* wqkvT = (u16*)(ws + 33554432ull);    //  24 MB  [6144][2048]
  u16* woutT = (u16*)(ws + 58720256ull);    //   8 MB  [2048][2048]
  u16* Qb    = (u16*)(ws + 67108864ull);    //  32 MB  [64][2048][128]
  u16* Kb    = (u16*)(ws + 100663296ull);   //  32 MB  [64][2048][128]
  u16* Vt    = (u16*)(ws + 134217728ull);   //  32 MB  [64][128][2048]
  u16* AO    = xb;                          //  alias: xb dead after GEMM1
  float* out = (float*)d_out;

  k_convert<<<8192, 256, 0, stream>>>(x, xb, 16777216);
  k_transpose_cvt<<<dim3(192, 64), dim3(32, 8), 0, stream>>>(w_qkv, wqkvT, 2048, 6144);
  k_transpose_cvt<<<dim3(64, 64),  dim3(32, 8), 0, stream>>>(w_out, woutT, 2048, 2048);
  k_gemm_bt<0><<<dim3(64, 48), 256, 0, stream>>>(xb, wqkvT, b_qkv, Qb, Kb, Vt, nullptr);
  k_rope<<<4096, 256, 0, stream>>>(Qb, Kb, rc, rs);
  k_attn<<<dim3(32, 64), 256, 0, stream>>>(Qb, Kb, Vt, AO);
  k_gemm_bt<1><<<dim3(64, 16), 256, 0, stream>>>(AO, woutT, b_out, nullptr, nullptr, nullptr, out);
}

// Round 3
// 801.579 us; speedup vs baseline: 1.1607x; 1.1607x over previous
//
#include <hip/hip_runtime.h>
#include <stdint.h>

#define B_  4
#define S_  2048
#define DM_ 2048
#define NH_ 16
#define HD_ 128

typedef unsigned short u16;
typedef unsigned int   u32;
typedef __attribute__((ext_vector_type(8))) short short8;
typedef __attribute__((ext_vector_type(8))) unsigned short u16x8;
typedef __attribute__((ext_vector_type(4))) float f32x4;

__device__ __forceinline__ u16 f2b(float f){
  union { float f; unsigned u; } v; v.f = f;
  return (u16)((v.u + 0x7fffu + ((v.u >> 16) & 1u)) >> 16);
}
__device__ __forceinline__ float b2f(u16 b){
  union { unsigned u; float f; } v; v.u = ((unsigned)b) << 16; return v.f;
}
__device__ __forceinline__ void gld_lds16(const void* g, void* l){
  __builtin_amdgcn_global_load_lds(
    (const __attribute__((address_space(1))) unsigned int*)(uintptr_t)g,
    (__attribute__((address_space(3))) unsigned int*)(uintptr_t)l, 16, 0, 0);
}

// ---------------- fp32 -> bf16 convert (vectorized) ----------------
__global__ void k_convert(const float* __restrict__ in, u16* __restrict__ out, int n){
  int i = (blockIdx.x * 256 + threadIdx.x) * 8;
  if (i >= n) return;
  float4 a = *(const float4*)(in + i);
  float4 b = *(const float4*)(in + i + 4);
  u16x8 o;
  o[0]=f2b(a.x); o[1]=f2b(a.y); o[2]=f2b(a.z); o[3]=f2b(a.w);
  o[4]=f2b(b.x); o[5]=f2b(b.y); o[6]=f2b(b.z); o[7]=f2b(b.w);
  *(u16x8*)(out + i) = o;
}

// ------------- transpose + convert: in[R][C] f32 -> out[C][R] bf16 -------------
__global__ void k_transpose_cvt(const float* __restrict__ in, u16* __restrict__ out,
                                int R, int C){
  __shared__ u16 tile[32][33];
  int tx = threadIdx.x, ty = threadIdx.y;
  int c0 = blockIdx.x * 32, r0 = blockIdx.y * 32;
  #pragma unroll
  for (int i = 0; i < 4; i++){
    int r = r0 + ty + i * 8;
    tile[ty + i*8][tx] = f2b(in[(size_t)r * C + c0 + tx]);
  }
  __syncthreads();
  #pragma unroll
  for (int i = 0; i < 4; i++){
    int c = c0 + ty + i * 8;
    out[(size_t)c * R + r0 + tx] = tile[tx][ty + i*8];
  }
}

// ---------------- GEMM (A[M][2048] x BT[N][2048]^T), m97 structure ----------------
template<int EPI>
__global__ __launch_bounds__(256, 2) void k_gemm_bt(
    const u16* __restrict__ A, const u16* __restrict__ BT,
    const float* __restrict__ bias,
    u16* __restrict__ Qd, u16* __restrict__ Kd, u16* __restrict__ Vd,
    float* __restrict__ Cout)
{
  __shared__ u16 As[128 * 32];
  __shared__ u16 Bs[128 * 32];
  const int lane = threadIdx.x & 63;
  const int wid  = threadIdx.x >> 6;
  const int wr = wid >> 1, wc = wid & 1;
  const int m0 = blockIdx.x * 128;
  const int n0 = blockIdx.y * 128;
  f32x4 acc[4][4] = {};
  const int fr = lane & 15;
  const int ks = (lane >> 4) * 8;

  for (int k0 = 0; k0 < 2048; k0 += 32){
    __syncthreads();
    #pragma unroll
    for (int t = 0; t < 2; t++){
      const int ob  = wid * 2048 + t * 1024 + lane * 16;
      const int row = ob >> 6, colb = ob & 63;
      gld_lds16(A  + (size_t)(m0 + row) * 2048 + k0 + (colb >> 1),
                (char*)As + wid * 2048 + t * 1024);
      gld_lds16(BT + (size_t)(n0 + row) * 2048 + k0 + (colb >> 1),
                (char*)Bs + wid * 2048 + t * 1024);
    }
    __syncthreads();
    short8 af[4], bf[4];
    #pragma unroll
    for (int i = 0; i < 4; i++) af[i] = *(const short8*)&As[(wr*64 + i*16 + fr)*32 + ks];
    #pragma unroll
    for (int i = 0; i < 4; i++) bf[i] = *(const short8*)&Bs[(wc*64 + i*16 + fr)*32 + ks];
    #pragma unroll
    for (int i = 0; i < 4; i++)
      #pragma unroll
      for (int j = 0; j < 4; j++)
        acc[i][j] = __builtin_amdgcn_mfma_f32_16x16x32_bf16(af[i], bf[j], acc[i][j], 0, 0, 0);
  }

  const int rowb = m0 + wr*64 + (lane >> 4) * 4;
  const int colb = n0 + wc*64 + (lane & 15);
  #pragma unroll
  for (int ni = 0; ni < 4; ni++){
    const int col = colb + ni * 16;
    const float bv = bias[col];
    if (EPI == 0){
      const int qkv = col >> 11, hd = col & 2047, h = hd >> 7, d = hd & 127;
      u16* dst = (qkv == 0) ? Qd : ((qkv == 1) ? Kd : Vd);
      #pragma unroll
      for (int mi = 0; mi < 4; mi++){
        f32x4 c = acc[mi][ni];
        #pragma unroll
        for (int j = 0; j < 4; j++){
          const int row = rowb + mi * 16 + j;
          const int b = row >> 11, s = row & 2047;
          size_t idx;
          if (qkv == 2) idx = ((size_t)((b * NH_ + h) * HD_ + d)) * S_ + s;  // V transposed
          else          idx = ((size_t)((b * NH_ + h) * S_  + s)) * HD_ + d;
          dst[idx] = f2b(c[j] + bv);
        }
      }
    } else {
      #pragma unroll
      for (int mi = 0; mi < 4; mi++){
        f32x4 c = acc[mi][ni];
        #pragma unroll
        for (int j = 0; j < 4; j++){
          const int row = rowb + mi * 16 + j;
          Cout[(size_t)row * 2048 + col] = c[j] + bv;
        }
      }
    }
  }
}

// ---------------- RoPE (interleaved pairs), in-place on Q and K ----------------
__global__ void k_rope(u16* __restrict__ Qb, u16* __restrict__ Kb,
                       const float* __restrict__ rc, const float* __restrict__ rs){
  const int gid = blockIdx.x * 256 + threadIdx.x;
  const int seg = gid & 3;
  const int row = gid >> 2;
  const int NR  = B_ * NH_ * S_;
  u16* base = (row < NR) ? (Qb + (size_t)row * HD_) : (Kb + (size_t)(row - NR) * HD_);
  const int s  = row & (S_ - 1);
  const int d0 = seg * 32;
  u16x8 v[4];
  #pragma unroll
  for (int t = 0; t < 4; t++) v[t] = *(u16x8*)(base + d0 + t * 8);
  float c[16], sn[16];
  const float4* cp = (const float4*)(rc + (size_t)s * 64 + seg * 16);
  const float4* sp = (const float4*)(rs + (size_t)s * 64 + seg * 16);
  #pragma unroll
  for (int t = 0; t < 4; t++){
    float4 cv = cp[t], sv = sp[t];
    c[t*4+0]=cv.x; c[t*4+1]=cv.y; c[t*4+2]=cv.z; c[t*4+3]=cv.w;
    sn[t*4+0]=sv.x; sn[t*4+1]=sv.y; sn[t*4+2]=sv.z; sn[t*4+3]=sv.w;
  }
  #pragma unroll
  for (int p = 0; p < 16; p++){
    int t = p >> 2, l = (2 * p) & 7;
    float e = b2f(v[t][l]), o = b2f(v[t][l + 1]);
    v[t][l]     = f2b(e * c[p] - o * sn[p]);
    v[t][l + 1] = f2b(e * sn[p] + o * c[p]);
  }
  #pragma unroll
  for (int t = 0; t < 4; t++) *(u16x8*)(base + d0 + t * 8) = v[t];
}

// ---------------- causal flash attention (swapped QK^T, in-register softmax) ----
// grid (32, B*NH), 256 thr = 4 waves x 16 q-rows. KVB=64 per tile.
// Q [bh][s][128], K [bh][s][128], Vt [bh][128][s].
// S^T = mfma(K, Q): lane holds row q=lane&15, k = 16nf + 4g + j  (g=lane>>4)
#define KVB 64
__global__ __launch_bounds__(256, 4) void k_attn(
    const u16* __restrict__ Qb, const u16* __restrict__ Kb,
    const u16* __restrict__ Vtb, u16* __restrict__ Ob)
{
  const int bh = blockIdx.y;
  const int qt = (int)gridDim.x - 1 - (int)blockIdx.x;  // heavy blocks first
  const int lane = threadIdx.x & 63, wid = threadIdx.x >> 6;
  const int q = lane & 15, g = lane >> 4;
  const int b = bh >> 4, h = bh & 15;
  const u16* Qp = Qb  + (size_t)bh * S_ * HD_;
  const u16* Kp = Kb  + (size_t)bh * S_ * HD_;
  const u16* Vp = Vtb + (size_t)bh * HD_ * S_;
  __shared__ u16 Ks[KVB * HD_];   // 16KB: row r x 256B; 16B-slot y holds logical slot y^(r&15)
  __shared__ u16 Vs[HD_ * KVB];   // 16KB: row d x 128B; 16B-slot y holds logical slot y^(d&7)

  const int q0 = qt * 64 + wid * 16;
  const int q_abs = q0 + q;

  short8 qf[4];   // B operand: col=q, k-dim d = kk*32 + g*8 + e
  {
    const u16* qrow = Qp + (size_t)(q0 + q) * HD_ + g * 8;
    #pragma unroll
    for (int kk = 0; kk < 4; kk++) qf[kk] = *(const short8*)(qrow + kk * 32);
  }
  f32x4 oacc[8] = {};
  float mrun = -__builtin_inff(), lrun = 0.f;
  const float scale = 0.08838834764831845f;  // 1/sqrt(128)
  const int nt = qt + 1;
  const int base16 = wid * 256 + lane;

  for (int it = 0; it < nt; ++it){
    const int kv0 = it * KVB;
    __syncthreads();
    #pragma unroll
    for (int c = 0; c < 4; c++){
      const int idx = base16 + c * 64;
      const int r  = idx >> 4, y  = idx & 15;     // K: 64 rows x 16 slots
      const int r2 = idx >> 3, y2 = idx & 7;      // V: 128 rows x 8 slots
      gld_lds16(Kp + (size_t)(kv0 + r) * HD_ + ((y ^ (r & 15)) << 3),
                (char*)Ks + ((wid * 256 + c * 64) << 4));
      gld_lds16(Vp + (size_t)r2 * S_ + kv0 + ((y2 ^ (r2 & 7)) << 3),
                (char*)Vs + ((wid * 256 + c * 64) << 4));
    }
    __syncthreads();
    if (kv0 > q0 + 15) continue;   // wave-uniform; barrier count preserved

    // --- QK^T (swapped): sacc[nf] = S^T rows 16nf..16nf+15 ---
    f32x4 sacc[4] = {};
    const char* ksb = (const char*)Ks + q * 256;
    #pragma unroll
    for (int nf = 0; nf < 4; nf++)
      #pragma unroll
      for (int kk = 0; kk < 4; kk++){
        const int slot = (4 * kk + g) ^ q;
        short8 kf = *(const short8*)(ksb + nf * 4096 + slot * 16);
        sacc[nf] = __builtin_amdgcn_mfma_f32_16x16x32_bf16(kf, qf[kk], sacc[nf], 0, 0, 0);
      }

    // --- mask + in-register online softmax (row q local to lane) ---
    float p[4][4];
    float pmax = -__builtin_inff();
    #pragma unroll
    for (int nf = 0; nf < 4; nf++)
      #pragma unroll
      for (int j = 0; j < 4; j++){
        const int k_abs = kv0 + nf * 16 + 4 * g + j;
        const float sv = (k_abs <= q_abs) ? sacc[nf][j] * scale : -__builtin_inff();
        p[nf][j] = sv;
        pmax = fmaxf(pmax, sv);
      }
    pmax = fmaxf(pmax, __shfl_xor(pmax, 16));
    pmax = fmaxf(pmax, __shfl_xor(pmax, 32));
    const float mnew = fmaxf(mrun, pmax);
    const float sc = __expf(mrun - mnew);
    float rsum = 0.f;
    #pragma unroll
    for (int nf = 0; nf < 4; nf++)
      #pragma unroll
      for (int j = 0; j < 4; j++){
        const float e = __expf(p[nf][j] - mnew);
        p[nf][j] = e; rsum += e;
      }
    rsum += __shfl_xor(rsum, 16);
    rsum += __shfl_xor(rsum, 32);
    lrun = lrun * sc + rsum; mrun = mnew;

    float scr[4];
    #pragma unroll
    for (int j = 0; j < 4; j++) scr[j] = __shfl(sc, 4 * g + j);
    #pragma unroll
    for (int m = 0; m < 8; m++)
      #pragma unroll
      for (int j = 0; j < 4; j++) oacc[m][j] *= scr[j];

    // --- pack P to bf16 pairs: pk[nf][t] = (p[nf][2t], p[nf][2t+1]) ---
    u32 pk[4][2];
    #pragma unroll
    for (int nf = 0; nf < 4; nf++)
      #pragma unroll
      for (int t = 0; t < 2; t++)
        pk[nf][t] = (u32)f2b(p[nf][2*t]) | ((u32)f2b(p[nf][2*t+1]) << 16);

    // --- exchange P into PV A-fragment layout; PV ---
    const int s0 = q + (((2 * g    ) & 3) << 4);
    const int s1 = q + (((2 * g + 1) & 3) << 4);
    const bool hi = (g >> 1) != 0;   // nf = 2c + (g>>1)
    #pragma unroll
    for (int c = 0; c < 2; c++){
      const int A0 = __shfl((int)pk[2*c][0], s0), B0 = __shfl((int)pk[2*c+1][0], s0);
      const int A1 = __shfl((int)pk[2*c][1], s0), B1 = __shfl((int)pk[2*c+1][1], s0);
      const int A2 = __shfl((int)pk[2*c][0], s1), B2 = __shfl((int)pk[2*c+1][0], s1);
      const int A3 = __shfl((int)pk[2*c][1], s1), B3 = __shfl((int)pk[2*c+1][1], s1);
      union { int w[4]; short8 v; } pa;
      pa.w[0] = hi ? B0 : A0;
      pa.w[1] = hi ? B1 : A1;
      pa.w[2] = hi ? B2 : A2;
      pa.w[3] = hi ? B3 : A3;
      const int slot = (4 * c + g) ^ (q & 7);
      const char* vsb = (const char*)Vs + q * 128 + slot * 16;
      #pragma unroll
      for (int m = 0; m < 8; m++){
        short8 vf = *(const short8*)(vsb + m * 2048);
        oacc[m] = __builtin_amdgcn_mfma_f32_16x16x32_bf16(pa.v, vf, oacc[m], 0, 0, 0);
      }
    }
  }

  // --- epilogue: O rows = 4g+j, cols d = 16m+q ---
  const float inv = 1.0f / lrun;
  #pragma unroll
  for (int j = 0; j < 4; j++){
    const float linv = __shfl(inv, 4 * g + j);
    const int row = q0 + 4 * g + j;
    u16* orow = Ob + ((size_t)(b * S_ + row) * DM_) + h * HD_ + q;
    #pragma unroll
    for (int m = 0; m < 8; m++)
      orow[m * 16] = f2b(oacc[m][j] * linv);
  }
}

extern "C" void kernel_launch(void* const* d_in, const int* in_sizes, int n_in,
                              void* d_out, int out_size, void* d_ws, size_t ws_size,
                              hipStream_t stream) {
  const float* x     = (const float*)d_in[0];
  const float* w_qkv = (const float*)d_in[1];
  const float* b_qkv = (const float*)d_in[2];
  const float* w_out = (const float*)d_in[3];
  const float* b_out = (const float*)d_in[4];
  const float* rc    = (const float*)d_in[5];
  const float* rs    = (const float*)d_in[6];
  char* ws = (char*)d_ws;
  u16* xb    = (u16*)(ws);                  //  32 MB  x bf16 [8192][2048]  (reused as AO)
  u16* wqkvT = (u16*)(ws + 33554432ull);    //  24 MB  [6144][2048]
  u16* woutT = (u16*)(ws + 58720256ull);    //   8 MB  [2048][2048]
  u16* Qb    = (u16*)(ws + 67108864ull);    //  32 MB  [64][2048][128]
  u16* Kb    = (u16*)(ws + 100663296ull);   //  32 MB  [64][2048][128]
  u16* Vt    = (u16*)(ws + 134217728ull);   //  32 MB  [64][128][2048]
  u16* AO    = xb;
  float* out = (float*)d_out;

  k_convert<<<8192, 256, 0, stream>>>(x, xb, 16777216);
  k_transpose_cvt<<<dim3(192, 64), dim3(32, 8), 0, stream>>>(w_qkv, wqkvT, 2048, 6144);
  k_transpose_cvt<<<dim3(64, 64),  dim3(32, 8), 0, stream>>>(w_out, woutT, 2048, 2048);
  k_gemm_bt<0><<<dim3(64, 48), 256, 0, stream>>>(xb, wqkvT, b_qkv, Qb, Kb, Vt, nullptr);
  k_rope<<<4096, 256, 0, stream>>>(Qb, Kb, rc, rs);
  k_attn<<<dim3(32, 64), 256, 0, stream>>>(Qb, Kb, Vt, AO);
  k_gemm_bt<1><<<dim3(64, 16), 256, 0, stream>>>(AO, woutT, b_out, nullptr, nullptr, nullptr, out);
}

// Round 6
// 747.220 us; speedup vs baseline: 1.2452x; 1.0727x over previous
//
#include <hip/hip_runtime.h>
#include <stdint.h>

#define B_  4
#define S_  2048
#define DM_ 2048
#define NH_ 16
#define HD_ 128

typedef unsigned short u16;
typedef unsigned int   u32;
typedef __attribute__((ext_vector_type(8))) short short8;
typedef __attribute__((ext_vector_type(8))) unsigned short u16x8;
typedef __attribute__((ext_vector_type(4))) float f32x4;
typedef __attribute__((ext_vector_type(16))) float f32x16;

__device__ __forceinline__ u16 f2b(float f){
  union { float f; unsigned u; } v; v.f = f;
  return (u16)((v.u + 0x7fffu + ((v.u >> 16) & 1u)) >> 16);
}
__device__ __forceinline__ float b2f(u16 b){
  union { unsigned u; float f; } v; v.u = ((unsigned)b) << 16; return v.f;
}
__device__ __forceinline__ void gld_lds16(const void* g, void* l){
  __builtin_amdgcn_global_load_lds(
    (const __attribute__((address_space(1))) unsigned int*)(uintptr_t)g,
    (__attribute__((address_space(3))) unsigned int*)(uintptr_t)l, 16, 0, 0);
}

// ---------------- fp32 -> bf16 convert (vectorized) ----------------
__global__ void k_convert(const float* __restrict__ in, u16* __restrict__ out, int n){
  int i = (blockIdx.x * 256 + threadIdx.x) * 8;
  if (i >= n) return;
  float4 a = *(const float4*)(in + i);
  float4 b = *(const float4*)(in + i + 4);
  u16x8 o;
  o[0]=f2b(a.x); o[1]=f2b(a.y); o[2]=f2b(a.z); o[3]=f2b(a.w);
  o[4]=f2b(b.x); o[5]=f2b(b.y); o[6]=f2b(b.z); o[7]=f2b(b.w);
  *(u16x8*)(out + i) = o;
}

// ------------- transpose + convert: in[R][C] f32 -> out[C][R] bf16 -------------
__global__ void k_transpose_cvt(const float* __restrict__ in, u16* __restrict__ out,
                                int R, int C){
  __shared__ u16 tile[32][33];
  int tx = threadIdx.x, ty = threadIdx.y;
  int c0 = blockIdx.x * 32, r0 = blockIdx.y * 32;
  #pragma unroll
  for (int i = 0; i < 4; i++){
    int r = r0 + ty + i * 8;
    tile[ty + i*8][tx] = f2b(in[(size_t)r * C + c0 + tx]);
  }
  __syncthreads();
  #pragma unroll
  for (int i = 0; i < 4; i++){
    int c = c0 + ty + i * 8;
    out[(size_t)c * R + r0 + tx] = tile[tx][ty + i*8];
  }
}

// ---------------- GEMM (A[M][2048] x BT[N][2048]^T), m97 structure ----------------
template<int EPI>
__global__ __launch_bounds__(256, 2) void k_gemm_bt(
    const u16* __restrict__ A, const u16* __restrict__ BT,
    const float* __restrict__ bias,
    u16* __restrict__ Qd, u16* __restrict__ Kd, u16* __restrict__ Vd,
    float* __restrict__ Cout)
{
  __shared__ u16 As[128 * 32];
  __shared__ u16 Bs[128 * 32];
  const int lane = threadIdx.x & 63;
  const int wid  = threadIdx.x >> 6;
  const int wr = wid >> 1, wc = wid & 1;
  const int m0 = blockIdx.x * 128;
  const int n0 = blockIdx.y * 128;
  f32x4 acc[4][4] = {};
  const int fr = lane & 15;
  const int ks = (lane >> 4) * 8;

  for (int k0 = 0; k0 < 2048; k0 += 32){
    __syncthreads();
    #pragma unroll
    for (int t = 0; t < 2; t++){
      const int ob  = wid * 2048 + t * 1024 + lane * 16;
      const int row = ob >> 6, colb = ob & 63;
      gld_lds16(A  + (size_t)(m0 + row) * 2048 + k0 + (colb >> 1),
                (char*)As + wid * 2048 + t * 1024);
      gld_lds16(BT + (size_t)(n0 + row) * 2048 + k0 + (colb >> 1),
                (char*)Bs + wid * 2048 + t * 1024);
    }
    __syncthreads();
    short8 af[4], bf[4];
    #pragma unroll
    for (int i = 0; i < 4; i++) af[i] = *(const short8*)&As[(wr*64 + i*16 + fr)*32 + ks];
    #pragma unroll
    for (int i = 0; i < 4; i++) bf[i] = *(const short8*)&Bs[(wc*64 + i*16 + fr)*32 + ks];
    #pragma unroll
    for (int i = 0; i < 4; i++)
      #pragma unroll
      for (int j = 0; j < 4; j++)
        acc[i][j] = __builtin_amdgcn_mfma_f32_16x16x32_bf16(af[i], bf[j], acc[i][j], 0, 0, 0);
  }

  const int rowb = m0 + wr*64 + (lane >> 4) * 4;
  const int colb = n0 + wc*64 + (lane & 15);
  #pragma unroll
  for (int ni = 0; ni < 4; ni++){
    const int col = colb + ni * 16;
    const float bv = bias[col];
    if (EPI == 0){
      const int qkv = col >> 11, hd = col & 2047, h = hd >> 7, d = hd & 127;
      u16* dst = (qkv == 0) ? Qd : ((qkv == 1) ? Kd : Vd);
      #pragma unroll
      for (int mi = 0; mi < 4; mi++){
        f32x4 c = acc[mi][ni];
        #pragma unroll
        for (int j = 0; j < 4; j++){
          const int row = rowb + mi * 16 + j;
          const int b = row >> 11, s = row & 2047;
          size_t idx;
          if (qkv == 2) idx = ((size_t)((b * NH_ + h) * HD_ + d)) * S_ + s;  // V transposed
          else          idx = ((size_t)((b * NH_ + h) * S_  + s)) * HD_ + d;
          dst[idx] = f2b(c[j] + bv);
        }
      }
    } else {
      #pragma unroll
      for (int mi = 0; mi < 4; mi++){
        f32x4 c = acc[mi][ni];
        #pragma unroll
        for (int j = 0; j < 4; j++){
          const int row = rowb + mi * 16 + j;
          Cout[(size_t)row * 2048 + col] = c[j] + bv;
        }
      }
    }
  }
}

// ---------------- RoPE (interleaved pairs), in-place on Q and K ----------------
__global__ void k_rope(u16* __restrict__ Qb, u16* __restrict__ Kb,
                       const float* __restrict__ rc, const float* __restrict__ rs){
  const int gid = blockIdx.x * 256 + threadIdx.x;
  const int seg = gid & 3;
  const int row = gid >> 2;
  const int NR  = B_ * NH_ * S_;
  u16* base = (row < NR) ? (Qb + (size_t)row * HD_) : (Kb + (size_t)(row - NR) * HD_);
  const int s  = row & (S_ - 1);
  const int d0 = seg * 32;
  u16x8 v[4];
  #pragma unroll
  for (int t = 0; t < 4; t++) v[t] = *(u16x8*)(base + d0 + t * 8);
  float c[16], sn[16];
  const float4* cp = (const float4*)(rc + (size_t)s * 64 + seg * 16);
  const float4* sp = (const float4*)(rs + (size_t)s * 64 + seg * 16);
  #pragma unroll
  for (int t = 0; t < 4; t++){
    float4 cv = cp[t], sv = sp[t];
    c[t*4+0]=cv.x; c[t*4+1]=cv.y; c[t*4+2]=cv.z; c[t*4+3]=cv.w;
    sn[t*4+0]=sv.x; sn[t*4+1]=sv.y; sn[t*4+2]=sv.z; sn[t*4+3]=sv.w;
  }
  #pragma unroll
  for (int p = 0; p < 16; p++){
    int t = p >> 2, l = (2 * p) & 7;
    float e = b2f(v[t][l]), o = b2f(v[t][l + 1]);
    v[t][l]     = f2b(e * c[p] - o * sn[p]);
    v[t][l + 1] = f2b(e * sn[p] + o * c[p]);
  }
  #pragma unroll
  for (int t = 0; t < 4; t++) *(u16x8*)(base + d0 + t * 8) = v[t];
}

// ---------------- causal flash attention (32x32 MFMA, swapped QK^T) ----------------
// grid (16, B*NH), 256 thr = 4 waves x 32 q-rows (block = 128 rows). KVB=64.
// S^T = mfma_32x32x16(K, Q): lane holds q-col = lane&31, kv-row = (i&3)+8(i>>2)+4hi.
#define KVB 64
__global__ __launch_bounds__(256, 2) void k_attn(
    const u16* __restrict__ Qb, const u16* __restrict__ Kb,
    const u16* __restrict__ Vtb, u16* __restrict__ Ob)
{
  const int bh = blockIdx.y;
  const int qt = (int)gridDim.x - 1 - (int)blockIdx.x;  // heavy blocks first
  const int lane = threadIdx.x & 63, wid = threadIdx.x >> 6;
  const int q = lane & 31, hi = lane >> 5;
  const int b = bh >> 4, h = bh & 15;
  const u16* Qp = Qb  + (size_t)bh * S_ * HD_;
  const u16* Kp = Kb  + (size_t)bh * S_ * HD_;
  const u16* Vp = Vtb + (size_t)bh * HD_ * S_;
  __shared__ u16 Ks[KVB * HD_];   // 16KB: row r (256B); 16B-slot y holds logical y^(r&15)
  __shared__ u16 Vs[HD_ * KVB];   // 16KB: row d (128B); 16B-slot y holds logical y^(d&7)

  const int q0w  = qt * 128 + wid * 32;
  const int q_abs = q0w + q;

  short8 qf[8];   // B operand: col=q, k(d) = s*16 + hi*8 + e
  {
    const u16* qrow = Qp + (size_t)q_abs * HD_ + hi * 8;
    #pragma unroll
    for (int s = 0; s < 8; s++) qf[s] = *(const short8*)(qrow + s * 16);
  }
  f32x16 oacc[4] = {};    // PV out: col d = 32*n4 + q, row = (i&3)+8(i>>2)+4hi
  float mrun = -__builtin_inff(), lrun = 0.f;
  const float scale = 0.08838834764831845f;  // 1/sqrt(128)
  const int nt = 2 * qt + 2;
  const int base16 = wid * 256 + lane;

  for (int it = 0; it < nt; ++it){
    const int kv0 = it * KVB;
    __syncthreads();
    #pragma unroll
    for (int c = 0; c < 4; c++){
      const int idx = base16 + c * 64;
      const int r  = idx >> 4, y  = idx & 15;     // K: 64 rows x 16 slots
      const int r2 = idx >> 3, y2 = idx & 7;      // V: 128 rows x 8 slots
      gld_lds16(Kp + (size_t)(kv0 + r) * HD_ + ((y ^ (r & 15)) << 3),
                (char*)Ks + ((wid * 256 + c * 64) << 4));
      gld_lds16(Vp + (size_t)r2 * S_ + kv0 + ((y2 ^ (r2 & 7)) << 3),
                (char*)Vs + ((wid * 256 + c * 64) << 4));
    }
    __syncthreads();
    if (kv0 > q0w + 31) continue;   // wave-uniform; barrier count preserved

    // --- QK^T (swapped): sacc[kb] = S^T rows kb*32..kb*32+31, cols = q ---
    f32x16 sacc[2] = {};
    #pragma unroll
    for (int s = 0; s < 8; s++)
      #pragma unroll
      for (int kb = 0; kb < 2; kb++){
        const int row  = kb * 32 + q;
        const int slot = (2 * s + hi) ^ (q & 15);
        short8 kf = *(const short8*)((const char*)Ks + row * 256 + slot * 16);
        sacc[kb] = __builtin_amdgcn_mfma_f32_32x32x16_bf16(kf, qf[s], sacc[kb], 0, 0, 0);
      }

    // --- mask + in-register online softmax (row q local to lane pair) ---
    float pmax = -__builtin_inff();
    #pragma unroll
    for (int kb = 0; kb < 2; kb++)
      #pragma unroll
      for (int i = 0; i < 16; i++){
        const int k_abs = kv0 + kb * 32 + (i & 3) + 8 * (i >> 2) + 4 * hi;
        const float sv = (k_abs <= q_abs) ? sacc[kb][i] * scale : -__builtin_inff();
        sacc[kb][i] = sv;
        pmax = fmaxf(pmax, sv);
      }
    pmax = fmaxf(pmax, __shfl_xor(pmax, 32));
    const float mnew = fmaxf(mrun, pmax);
    const float sc = __expf(mrun - mnew);
    float rsum = 0.f;
    #pragma unroll
    for (int kb = 0; kb < 2; kb++)
      #pragma unroll
      for (int i = 0; i < 16; i++){
        const float e = __expf(sacc[kb][i] - mnew);
        sacc[kb][i] = e; rsum += e;
      }
    rsum += __shfl_xor(rsum, 32);
    lrun = lrun * sc + rsum; mrun = mnew;

    // --- rescale O (rows indexed by i, per-row sc via shuffle) ---
    #pragma unroll
    for (int i = 0; i < 16; i++){
      const float s_i = __shfl(sc, (i & 3) + 8 * (i >> 2) + 4 * hi);
      #pragma unroll
      for (int n4 = 0; n4 < 4; n4++) oacc[n4][i] *= s_i;
    }

    // --- pack P pairs: wds[kb][t] = (p[2t], p[2t+1]) -> kv pair (consecutive) ---
    u32 wds[2][8];
    #pragma unroll
    for (int kb = 0; kb < 2; kb++)
      #pragma unroll
      for (int t = 0; t < 8; t++)
        wds[kb][t] = (u32)f2b(sacc[kb][2*t]) | ((u32)f2b(sacc[kb][2*t+1]) << 16);

    // --- exchange into PV A-fragments + PV ---
    #pragma unroll
    for (int sp = 0; sp < 4; sp++){           // K-step: kv = 16*sp + 8*hi + e
      const int kb = sp >> 1, hh = sp & 1;
      const u32 w0 = wds[kb][4*hh+0], w1 = wds[kb][4*hh+1];
      const u32 w2 = wds[kb][4*hh+2], w3 = wds[kb][4*hh+3];
      const int x0 = __shfl((int)w0, q + 32);   // hi=1 partner's w0
      const int x1 = __shfl((int)w1, q + 32);
      const int y0 = __shfl((int)w2, q);        // hi=0 partner's w2
      const int y1 = __shfl((int)w3, q);
      union { int w[4]; short8 v; } pa;
      pa.w[0] = hi ? y0 : (int)w0;
      pa.w[1] = hi ? y1 : (int)w1;
      pa.w[2] = hi ? (int)w2 : x0;
      pa.w[3] = hi ? (int)w3 : x1;
      #pragma unroll
      for (int n4 = 0; n4 < 4; n4++){
        const int d = n4 * 32 + q;
        const int slot = (2 * sp + hi) ^ (d & 7);
        short8 vf = *(const short8*)((const char*)Vs + d * 128 + slot * 16);
        oacc[n4] = __builtin_amdgcn_mfma_f32_32x32x16_bf16(pa.v, vf, oacc[n4], 0, 0, 0);
      }
    }
  }

  // --- epilogue: O rows = (i&3)+8(i>>2)+4hi, cols d = 32*n4 + q ---
  const float inv = 1.0f / lrun;
  #pragma unroll
  for (int i = 0; i < 16; i++){
    const int r = (i & 3) + 8 * (i >> 2) + 4 * hi;
    const float linv = __shfl(inv, r);
    const int row = q0w + r;
    u16* orow = Ob + ((size_t)(b * S_ + row) * DM_) + h * HD_ + q;
    #pragma unroll
    for (int n4 = 0; n4 < 4; n4++)
      orow[n4 * 32] = f2b(oacc[n4][i] * linv);
  }
}

extern "C" void kernel_launch(void* const* d_in, const int* in_sizes, int n_in,
                              void* d_out, int out_size, void* d_ws, size_t ws_size,
                              hipStream_t stream) {
  const float* x     = (const float*)d_in[0];
  const float* w_qkv = (const float*)d_in[1];
  const float* b_qkv = (const float*)d_in[2];
  const float* w_out = (const float*)d_in[3];
  const float* b_out = (const float*)d_in[4];
  const float* rc    = (const float*)d_in[5];
  const float* rs    = (const float*)d_in[6];
  char* ws = (char*)d_ws;
  u16* xb    = (u16*)(ws);                  //  32 MB  x bf16 [8192][2048]  (reused as AO)
  u16* wqkvT = (u16*)(ws + 33554432ull);    //  24 MB  [6144][2048]
  u16* woutT = (u16*)(ws + 58720256ull);    //   8 MB  [2048][2048]
  u16* Qb    = (u16*)(ws + 67108864ull);    //  32 MB  [64][2048][128]
  u16* Kb    = (u16*)(ws + 100663296ull);   //  32 MB  [64][2048][128]
  u16* Vt    = (u16*)(ws + 134217728ull);   //  32 MB  [64][128][2048]
  u16* AO    = xb;
  float* out = (float*)d_out;

  k_convert<<<8192, 256, 0, stream>>>(x, xb, 16777216);
  k_transpose_cvt<<<dim3(192, 64), dim3(32, 8), 0, stream>>>(w_qkv, wqkvT, 2048, 6144);
  k_transpose_cvt<<<dim3(64, 64),  dim3(32, 8), 0, stream>>>(w_out, woutT, 2048, 2048);
  k_gemm_bt<0><<<dim3(64, 48), 256, 0, stream>>>(xb, wqkvT, b_qkv, Qb, Kb, Vt, nullptr);
  k_rope<<<4096, 256, 0, stream>>>(Qb, Kb, rc, rs);
  k_attn<<<dim3(16, 64), 256, 0, stream>>>(Qb, Kb, Vt, AO);
  k_gemm_bt<1><<<dim3(64, 16), 256, 0, stream>>>(AO, woutT, b_out, nullptr, nullptr, nullptr, out);
}

// Round 8
// 731.246 us; speedup vs baseline: 1.2724x; 1.0218x over previous
//
#include <hip/hip_runtime.h>
#include <stdint.h>

#define B_  4
#define S_  2048
#define DM_ 2048
#define NH_ 16
#define HD_ 128

typedef unsigned short u16;
typedef unsigned int   u32;
typedef __attribute__((ext_vector_type(8))) short short8;
typedef __attribute__((ext_vector_type(8))) unsigned short u16x8;
typedef __attribute__((ext_vector_type(4))) float f32x4;
typedef __attribute__((ext_vector_type(16))) float f32x16;

__device__ __forceinline__ u16 f2b(float f){
  union { float f; unsigned u; } v; v.f = f;
  return (u16)((v.u + 0x7fffu + ((v.u >> 16) & 1u)) >> 16);
}
__device__ __forceinline__ float b2f(u16 b){
  union { unsigned u; float f; } v; v.u = ((unsigned)b) << 16; return v.f;
}
__device__ __forceinline__ void gld_lds16(const void* g, void* l){
  __builtin_amdgcn_global_load_lds(
    (const __attribute__((address_space(1))) unsigned int*)(uintptr_t)g,
    (__attribute__((address_space(3))) unsigned int*)(uintptr_t)l, 16, 0, 0);
}

// ---------------- fp32 -> bf16 convert (vectorized) ----------------
__global__ void k_convert(const float* __restrict__ in, u16* __restrict__ out, int n){
  int i = (blockIdx.x * 256 + threadIdx.x) * 8;
  if (i >= n) return;
  float4 a = *(const float4*)(in + i);
  float4 b = *(const float4*)(in + i + 4);
  u16x8 o;
  o[0]=f2b(a.x); o[1]=f2b(a.y); o[2]=f2b(a.z); o[3]=f2b(a.w);
  o[4]=f2b(b.x); o[5]=f2b(b.y); o[6]=f2b(b.z); o[7]=f2b(b.w);
  *(u16x8*)(out + i) = o;
}

// ------------- transpose + convert: in[R][C] f32 -> out[C][R] bf16 -------------
__global__ void k_transpose_cvt(const float* __restrict__ in, u16* __restrict__ out,
                                int R, int C){
  __shared__ u16 tile[32][33];
  int tx = threadIdx.x, ty = threadIdx.y;
  int c0 = blockIdx.x * 32, r0 = blockIdx.y * 32;
  #pragma unroll
  for (int i = 0; i < 4; i++){
    int r = r0 + ty + i * 8;
    tile[ty + i*8][tx] = f2b(in[(size_t)r * C + c0 + tx]);
  }
  __syncthreads();
  #pragma unroll
  for (int i = 0; i < 4; i++){
    int c = c0 + ty + i * 8;
    out[(size_t)c * R + r0 + tx] = tile[tx][ty + i*8];
  }
}

// ======== GEMM 256x256 tile, BK=64, 8 waves, counted-vmcnt double-buffer ========
// A[M][2048] x BT[N][2048]^T. K-tiles: 2048/64 = 32.
// LDS swizzle (T2): logical (R, Cl) stored at physical Cp = Cl ^ ((R&7)<<4).
// Staged via global_load_lds with inverse-swizzled GLOBAL source (rule 21).
// EPI==0: QKV scatter epilogue; EPI==1: fp32 + bias.
#define NT_K 32
template<int EPI>
__global__ __launch_bounds__(512, 1) void k_gemm256(
    const u16* __restrict__ A, const u16* __restrict__ BT,
    const float* __restrict__ bias,
    u16* __restrict__ Qd, u16* __restrict__ Kd, u16* __restrict__ Vd,
    float* __restrict__ Cout)
{
  __shared__ u16 As[2][256 * 64];   // 64 KB
  __shared__ u16 Bs[2][256 * 64];   // 64 KB
  const int tid  = threadIdx.x;
  const int lane = tid & 63, wid = tid >> 6;
  const int wr = wid >> 2, wc = wid & 3;       // 2 (M) x 4 (N) waves
  const int fr = lane & 15, g = lane >> 4;

  // T1: bijective XCD swizzle (gridDim.x % 8 == 0), then bm fastest (nbm=32)
  const int nwg = (int)gridDim.x;
  const int cpx = nwg >> 3;
  const int swz = ((int)blockIdx.x & 7) * cpx + ((int)blockIdx.x >> 3);
  const int m0 = (swz & 31) * 256;
  const int n0 = (swz >> 5) * 256;

  f32x4 acc[8][4] = {};

  // ---- staging: one K-tile (A 32KB + B 32KB), 8 gload_lds per thread ----
  auto STAGE = [&](int buf, int kt){
    const int k0 = kt * 64;
    #pragma unroll
    for (int c = 0; c < 4; c++){
      const int Lb = wid * 1024 + c * 8192;     // wave-uniform LDS byte base
      const int L  = Lb + lane * 16;            // this lane's byte
      const int R  = L >> 7;                    // tile row
      const int Cp = L & 127;                   // physical byte col
      const int Cl = Cp ^ ((R & 7) << 4);       // logical byte col (involution)
      gld_lds16(A  + (size_t)(m0 + R) * 2048 + k0 + (Cl >> 1), (char*)As[buf] + Lb);
      gld_lds16(BT + (size_t)(n0 + R) * 2048 + k0 + (Cl >> 1), (char*)Bs[buf] + Lb);
    }
  };
  // ---- swizzled fragment reads ----
  auto LDA = [&](int buf, int mi, int s) -> short8 {
    const int R  = wr * 128 + mi * 16 + fr;
    const int Cl = s * 64 + g * 16;
    return *(const short8*)((const char*)As[buf] + R * 128 + (Cl ^ ((R & 7) << 4)));
  };
  auto LDB = [&](int buf, int ni, int s) -> short8 {
    const int R  = wc * 64 + ni * 16 + fr;
    const int Cl = s * 64 + g * 16;
    return *(const short8*)((const char*)Bs[buf] + R * 128 + (Cl ^ ((R & 7) << 4)));
  };
  // ---- one K-tile of compute: 4 quadrant phases x 16 MFMA ----
  auto COMPUTE = [&](int buf){
    short8 a[4][2], b[4][2];
    #pragma unroll
    for (int mi = 0; mi < 4; mi++){ a[mi][0] = LDA(buf, mi, 0); a[mi][1] = LDA(buf, mi, 1); }
    #pragma unroll
    for (int ni = 0; ni < 2; ni++){ b[ni][0] = LDB(buf, ni, 0); b[ni][1] = LDB(buf, ni, 1); }
    __builtin_amdgcn_s_setprio(1);
    #pragma unroll
    for (int mi = 0; mi < 4; mi++)
      #pragma unroll
      for (int ni = 0; ni < 2; ni++)
        #pragma unroll
        for (int s = 0; s < 2; s++)
          acc[mi][ni] = __builtin_amdgcn_mfma_f32_16x16x32_bf16(a[mi][s], b[ni][s], acc[mi][ni], 0, 0, 0);
    __builtin_amdgcn_s_setprio(0);
    #pragma unroll
    for (int ni = 2; ni < 4; ni++){ b[ni][0] = LDB(buf, ni, 0); b[ni][1] = LDB(buf, ni, 1); }
    __builtin_amdgcn_s_setprio(1);
    #pragma unroll
    for (int mi = 0; mi < 4; mi++)
      #pragma unroll
      for (int ni = 2; ni < 4; ni++)
        #pragma unroll
        for (int s = 0; s < 2; s++)
          acc[mi][ni] = __builtin_amdgcn_mfma_f32_16x16x32_bf16(a[mi][s], b[ni][s], acc[mi][ni], 0, 0, 0);
    __builtin_amdgcn_s_setprio(0);
    #pragma unroll
    for (int mi = 0; mi < 4; mi++){ a[mi][0] = LDA(buf, mi + 4, 0); a[mi][1] = LDA(buf, mi + 4, 1); }
    __builtin_amdgcn_s_setprio(1);
    #pragma unroll
    for (int mi = 0; mi < 4; mi++)
      #pragma unroll
      for (int ni = 2; ni < 4; ni++)
        #pragma unroll
        for (int s = 0; s < 2; s++)
          acc[mi+4][ni] = __builtin_amdgcn_mfma_f32_16x16x32_bf16(a[mi][s], b[ni][s], acc[mi+4][ni], 0, 0, 0);
    __builtin_amdgcn_s_setprio(0);
    __builtin_amdgcn_s_setprio(1);
    #pragma unroll
    for (int mi = 0; mi < 4; mi++)
      #pragma unroll
      for (int ni = 0; ni < 2; ni++)
        #pragma unroll
        for (int s = 0; s < 2; s++)
          acc[mi+4][ni] = __builtin_amdgcn_mfma_f32_16x16x32_bf16(a[mi][s], b[ni][s], acc[mi+4][ni], 0, 0, 0);
    __builtin_amdgcn_s_setprio(0);
  };

  // ---- pipeline: 2-deep prefetch, counted vmcnt, raw barriers ----
  STAGE(0, 0);
  STAGE(1, 1);
  for (int t = 0; t < NT_K - 1; ++t){
    const int cur = t & 1;
    asm volatile("s_waitcnt vmcnt(8)" ::: "memory");   // tile t landed; t+1 in flight
    __builtin_amdgcn_s_barrier();
    __builtin_amdgcn_sched_barrier(0);
    COMPUTE(cur);
    __builtin_amdgcn_sched_barrier(0);
    __builtin_amdgcn_s_barrier();                      // all waves done reading buf cur
    __builtin_amdgcn_sched_barrier(0);
    if (t + 2 < NT_K) STAGE(cur, t + 2);
  }
  asm volatile("s_waitcnt vmcnt(0)" ::: "memory");
  __builtin_amdgcn_s_barrier();
  __builtin_amdgcn_sched_barrier(0);
  COMPUTE((NT_K - 1) & 1);

  // ---- epilogue ----
  const int rowb = m0 + wr * 128 + g * 4;
  const int colb = n0 + wc * 64 + fr;
  #pragma unroll
  for (int ni = 0; ni < 4; ni++){
    const int col = colb + ni * 16;
    const float bv = bias[col];
    if (EPI == 0){
      const int qkv = col >> 11, hd = col & 2047, h = hd >> 7, d = hd & 127;
      u16* dst = (qkv == 0) ? Qd : ((qkv == 1) ? Kd : Vd);
      #pragma unroll
      for (int mi = 0; mi < 8; mi++){
        f32x4 c = acc[mi][ni];
        #pragma unroll
        for (int j = 0; j < 4; j++){
          const int row = rowb + mi * 16 + j;
          const int b = row >> 11, s = row & 2047;
          size_t idx;
          if (qkv == 2) idx = ((size_t)((b * NH_ + h) * HD_ + d)) * S_ + s;  // V transposed
          else          idx = ((size_t)((b * NH_ + h) * S_  + s)) * HD_ + d;
          dst[idx] = f2b(c[j] + bv);
        }
      }
    } else {
      #pragma unroll
      for (int mi = 0; mi < 8; mi++){
        f32x4 c = acc[mi][ni];
        #pragma unroll
        for (int j = 0; j < 4; j++){
          const int row = rowb + mi * 16 + j;
          Cout[(size_t)row * 2048 + col] = c[j] + bv;
        }
      }
    }
  }
}

// ---------------- RoPE (interleaved pairs), in-place on Q and K ----------------
__global__ void k_rope(u16* __restrict__ Qb, u16* __restrict__ Kb,
                       const float* __restrict__ rc, const float* __restrict__ rs){
  const int gid = blockIdx.x * 256 + threadIdx.x;
  const int seg = gid & 3;
  const int row = gid >> 2;
  const int NR  = B_ * NH_ * S_;
  u16* base = (row < NR) ? (Qb + (size_t)row * HD_) : (Kb + (size_t)(row - NR) * HD_);
  const int s  = row & (S_ - 1);
  const int d0 = seg * 32;
  u16x8 v[4];
  #pragma unroll
  for (int t = 0; t < 4; t++) v[t] = *(u16x8*)(base + d0 + t * 8);
  float c[16], sn[16];
  const float4* cp = (const float4*)(rc + (size_t)s * 64 + seg * 16);
  const float4* sp = (const float4*)(rs + (size_t)s * 64 + seg * 16);
  #pragma unroll
  for (int t = 0; t < 4; t++){
    float4 cv = cp[t], sv = sp[t];
    c[t*4+0]=cv.x; c[t*4+1]=cv.y; c[t*4+2]=cv.z; c[t*4+3]=cv.w;
    sn[t*4+0]=sv.x; sn[t*4+1]=sv.y; sn[t*4+2]=sv.z; sn[t*4+3]=sv.w;
  }
  #pragma unroll
  for (int p = 0; p < 16; p++){
    int t = p >> 2, l = (2 * p) & 7;
    float e = b2f(v[t][l]), o = b2f(v[t][l + 1]);
    v[t][l]     = f2b(e * c[p] - o * sn[p]);
    v[t][l + 1] = f2b(e * sn[p] + o * c[p]);
  }
  #pragma unroll
  for (int t = 0; t < 4; t++) *(u16x8*)(base + d0 + t * 8) = v[t];
}

// ---------------- causal flash attention (32x32 MFMA, swapped QK^T) ----------------
// grid (16, B*NH), 256 thr = 4 waves x 32 q-rows (block = 128 rows). KVB=64.
#define KVB 64
__global__ __launch_bounds__(256, 2) void k_attn(
    const u16* __restrict__ Qb, const u16* __restrict__ Kb,
    const u16* __restrict__ Vtb, u16* __restrict__ Ob)
{
  const int bh = blockIdx.y;
  const int qt = (int)gridDim.x - 1 - (int)blockIdx.x;  // heavy blocks first
  const int lane = threadIdx.x & 63, wid = threadIdx.x >> 6;
  const int q = lane & 31, hi = lane >> 5;
  const int b = bh >> 4, h = bh & 15;
  const u16* Qp = Qb  + (size_t)bh * S_ * HD_;
  const u16* Kp = Kb  + (size_t)bh * S_ * HD_;
  const u16* Vp = Vtb + (size_t)bh * HD_ * S_;
  __shared__ u16 Ks[KVB * HD_];   // 16KB: row r (256B); 16B-slot y holds logical y^(r&15)
  __shared__ u16 Vs[HD_ * KVB];   // 16KB: row d (128B); 16B-slot y holds logical y^(d&7)

  const int q0w  = qt * 128 + wid * 32;
  const int q_abs = q0w + q;

  short8 qf[8];   // B operand: col=q, k(d) = s*16 + hi*8 + e
  {
    const u16* qrow = Qp + (size_t)q_abs * HD_ + hi * 8;
    #pragma unroll
    for (int s = 0; s < 8; s++) qf[s] = *(const short8*)(qrow + s * 16);
  }
  f32x16 oacc[4] = {};    // PV out: col d = 32*n4 + q, row = (i&3)+8(i>>2)+4hi
  float mrun = -__builtin_inff(), lrun = 0.f;
  const float scale = 0.08838834764831845f;  // 1/sqrt(128)
  const int nt = 2 * qt + 2;
  const int base16 = wid * 256 + lane;

  for (int it = 0; it < nt; ++it){
    const int kv0 = it * KVB;
    __syncthreads();
    #pragma unroll
    for (int c = 0; c < 4; c++){
      const int idx = base16 + c * 64;
      const int r  = idx >> 4, y  = idx & 15;     // K: 64 rows x 16 slots
      const int r2 = idx >> 3, y2 = idx & 7;      // V: 128 rows x 8 slots
      gld_lds16(Kp + (size_t)(kv0 + r) * HD_ + ((y ^ (r & 15)) << 3),
                (char*)Ks + ((wid * 256 + c * 64) << 4));
      gld_lds16(Vp + (size_t)r2 * S_ + kv0 + ((y2 ^ (r2 & 7)) << 3),
                (char*)Vs + ((wid * 256 + c * 64) << 4));
    }
    __syncthreads();
    if (kv0 > q0w + 31) continue;   // wave-uniform; barrier count preserved

    // --- QK^T (swapped): sacc[kb] = S^T rows kb*32..kb*32+31, cols = q ---
    f32x16 sacc[2] = {};
    #pragma unroll
    for (int s = 0; s < 8; s++)
      #pragma unroll
      for (int kb = 0; kb < 2; kb++){
        const int row  = kb * 32 + q;
        const int slot = (2 * s + hi) ^ (q & 15);
        short8 kf = *(const short8*)((const char*)Ks + row * 256 + slot * 16);
        sacc[kb] = __builtin_amdgcn_mfma_f32_32x32x16_bf16(kf, qf[s], sacc[kb], 0, 0, 0);
      }

    // --- mask + in-register online softmax (row q local to lane pair) ---
    float pmax = -__builtin_inff();
    #pragma unroll
    for (int kb = 0; kb < 2; kb++)
      #pragma unroll
      for (int i = 0; i < 16; i++){
        const int k_abs = kv0 + kb * 32 + (i & 3) + 8 * (i >> 2) + 4 * hi;
        const float sv = (k_abs <= q_abs) ? sacc[kb][i] * scale : -__builtin_inff();
        sacc[kb][i] = sv;
        pmax = fmaxf(pmax, sv);
      }
    pmax = fmaxf(pmax, __shfl_xor(pmax, 32));
    const float mnew = fmaxf(mrun, pmax);
    const float sc = __expf(mrun - mnew);
    float rsum = 0.f;
    #pragma unroll
    for (int kb = 0; kb < 2; kb++)
      #pragma unroll
      for (int i = 0; i < 16; i++){
        const float e = __expf(sacc[kb][i] - mnew);
        sacc[kb][i] = e; rsum += e;
      }
    rsum += __shfl_xor(rsum, 32);
    lrun = lrun * sc + rsum; mrun = mnew;

    // --- rescale O (rows indexed by i, per-row sc via shuffle) ---
    #pragma unroll
    for (int i = 0; i < 16; i++){
      const float s_i = __shfl(sc, (i & 3) + 8 * (i >> 2) + 4 * hi);
      #pragma unroll
      for (int n4 = 0; n4 < 4; n4++) oacc[n4][i] *= s_i;
    }

    // --- pack P pairs ---
    u32 wds[2][8];
    #pragma unroll
    for (int kb = 0; kb < 2; kb++)
      #pragma unroll
      for (int t = 0; t < 8; t++)
        wds[kb][t] = (u32)f2b(sacc[kb][2*t]) | ((u32)f2b(sacc[kb][2*t+1]) << 16);

    // --- exchange into PV A-fragments + PV ---
    #pragma unroll
    for (int sp = 0; sp < 4; sp++){           // K-step: kv = 16*sp + 8*hi + e
      const int kb = sp >> 1, hh = sp & 1;
      const u32 w0 = wds[kb][4*hh+0], w1 = wds[kb][4*hh+1];
      const u32 w2 = wds[kb][4*hh+2], w3 = wds[kb][4*hh+3];
      const int x0 = __shfl((int)w0, q + 32);   // hi=1 partner's w0
      const int x1 = __shfl((int)w1, q + 32);
      const int y0 = __shfl((int)w2, q);        // hi=0 partner's w2
      const int y1 = __shfl((int)w3, q);
      union { int w[4]; short8 v; } pa;
      pa.w[0] = hi ? y0 : (int)w0;
      pa.w[1] = hi ? y1 : (int)w1;
      pa.w[2] = hi ? (int)w2 : x0;
      pa.w[3] = hi ? (int)w3 : x1;
      #pragma unroll
      for (int n4 = 0; n4 < 4; n4++){
        const int d = n4 * 32 + q;
        const int slot = (2 * sp + hi) ^ (d & 7);
        short8 vf = *(const short8*)((const char*)Vs + d * 128 + slot * 16);
        oacc[n4] = __builtin_amdgcn_mfma_f32_32x32x16_bf16(pa.v, vf, oacc[n4], 0, 0, 0);
      }
    }
  }

  // --- epilogue ---
  const float inv = 1.0f / lrun;
  #pragma unroll
  for (int i = 0; i < 16; i++){
    const int r = (i & 3) + 8 * (i >> 2) + 4 * hi;
    const float linv = __shfl(inv, r);
    const int row = q0w + r;
    u16* orow = Ob + ((size_t)(b * S_ + row) * DM_) + h * HD_ + q;
    #pragma unroll
    for (int n4 = 0; n4 < 4; n4++)
      orow[n4 * 32] = f2b(oacc[n4][i] * linv);
  }
}

extern "C" void kernel_launch(void* const* d_in, const int* in_sizes, int n_in,
                              void* d_out, int out_size, void* d_ws, size_t ws_size,
                              hipStream_t stream) {
  const float* x     = (const float*)d_in[0];
  const float* w_qkv = (const float*)d_in[1];
  const float* b_qkv = (const float*)d_in[2];
  const float* w_out = (const float*)d_in[3];
  const float* b_out = (const float*)d_in[4];
  const float* rc    = (const float*)d_in[5];
  const float* rs    = (const float*)d_in[6];
  char* ws = (char*)d_ws;
  u16* xb    = (u16*)(ws);                  //  32 MB  x bf16 [8192][2048]  (reused as AO)
  u16* wqkvT = (u16*)(ws + 33554432ull);    //  24 MB  [6144][2048]
  u16* woutT = (u16*)(ws + 58720256ull);    //   8 MB  [2048][2048]
  u16* Qb    = (u16*)(ws + 67108864ull);    //  32 MB  [64][2048][128]
  u16* Kb    = (u16*)(ws + 100663296ull);   //  32 MB  [64][2048][128]
  u16* Vt    = (u16*)(ws + 134217728ull);   //  32 MB  [64][128][2048]
  u16* AO    = xb;
  float* out = (float*)d_out;

  k_convert<<<8192, 256, 0, stream>>>(x, xb, 16777216);
  k_transpose_cvt<<<dim3(192, 64), dim3(32, 8), 0, stream>>>(w_qkv, wqkvT, 2048, 6144);
  k_transpose_cvt<<<dim3(64, 64),  dim3(32, 8), 0, stream>>>(w_out, woutT, 2048, 2048);
  k_gemm256<0><<<768, 512, 0, stream>>>(xb, wqkvT, b_qkv, Qb, Kb, Vt, nullptr);   // 32 x 24 blocks
  k_rope<<<4096, 256, 0, stream>>>(Qb, Kb, rc, rs);
  k_attn<<<dim3(16, 64), 256, 0, stream>>>(Qb, Kb, Vt, AO);
  k_gemm256<1><<<256, 512, 0, stream>>>(AO, woutT, b_out, nullptr, nullptr, nullptr, out); // 32 x 8
}